// Round 3
// baseline (96.179 us; speedup 1.0000x reference)
//
#include <hip/hip_runtime.h>
#include <cstdint>

// y[m][n] = sum_k x[m][k] * (q[n][k] * scale[n]) + bias[n]
// M=32, K=8192, N=8192; q = signed int4 nibbles packed 8 per int32.
// Harness dtype reality (verified round 4): fp16 tensors are FLOAT32 on
// device (inputs and output); b_packed is int32. ws_size ~268 MB.
//
// Round 7: round-0 structure (best measured) + NON-TEMPORAL B loads.
// Mechanism: the timed graph's 268 MB workspace poison dirties all of
// L2+L3 (256 MB); every B-read line then allocates by evicting a dirty
// line -> forced writeback interleaved with our read stream -> effective
// read BW ~530 GB/s (measured R1: all pipes idle at BOTH 40% and ~80%
// occupancy => not a latency-hiding problem). B has zero reuse, so `nt`
// loads skip allocation and decouple the read stream from dirty evictions.
// Output stores are nt too (write-once). xp stays cached (heavy L2 reuse).
#define M_DIM 32
#define K_DIM 8192
#define N_DIM 8192

typedef _Float16 f16x8 __attribute__((ext_vector_type(8)));
typedef _Float16 f16x2 __attribute__((ext_vector_type(2)));
typedef float    f32x4 __attribute__((ext_vector_type(4)));
typedef uint32_t u32x4 __attribute__((ext_vector_type(4)));

// Magic-bias dequant: dword (8 nibbles) -> 8 exact f16 in [-8,7].
// t_s = ((w>>4s) & 0x000F000F) ^ 0x64086408 = f16x2 {1024+(n_s^8), 1024+(n_{s+4}^8)}
// minus 1032.0 -> {val(n_s), val(n_{s+4})} exactly (integers < 2048, exact f16).
// Fragment element j therefore holds nibble kp[j] = (j>>1) + (j&1)*4; xprep
// bakes the SAME permutation into the A layout, so the MFMA dot is exact.
__device__ __forceinline__ f16x8 dq8(uint32_t w) {
  union { uint32_t u[4]; f16x8 v; } r;
  const uint32_t MASK  = 0x000F000Fu;
  const uint32_t MAGIC = 0x64086408u;                 // f16x2 {1032, 1032}
  const f16x2 magic = __builtin_bit_cast(f16x2, MAGIC);
#pragma unroll
  for (int s = 0; s < 4; ++s) {
    uint32_t t = ((w >> (4 * s)) & MASK) ^ MAGIC;
    f16x2 h = __builtin_bit_cast(f16x2, t) - magic;   // v_pk_add_f16 (neg)
    r.u[s] = __builtin_bit_cast(uint32_t, h);
  }
  return r.v;
}

// -------- x prep: f32 x[32][8192] -> f16 xp[g=k/8][m][8], nibble-pair perm --
// Element j of each 8-group = x[k = g*8 + (j>>1) + (j&1)*4]  (interleave lo/hi).
__global__ __launch_bounds__(256) void xprep_kernel(
    const float* __restrict__ x, uint4* __restrict__ xp) {
  const int T = blockIdx.x * 256 + threadIdx.x;  // 0..32767
  const int m = T >> 10;                         // 0..31
  const int g = T & 1023;                        // 0..1023
  const f32x4* p = (const f32x4*)(x + (size_t)m * K_DIM + (size_t)g * 8);
  f32x4 lo = p[0], hi = p[1];
  union { uint4 q; f16x8 v; } o;
#pragma unroll
  for (int s = 0; s < 4; ++s) {
    o.v[2 * s]     = (_Float16)lo[s];            // nibble-pair perm: {lo_s, hi_s}
    o.v[2 * s + 1] = (_Float16)hi[s];
  }
  xp[(size_t)g * 32 + m] = o.q;                  // cached: gemm re-reads from L2
}

// -------- main GEMM: 256 WGs x 1024 thr (16 waves) -------------------------
// WG = 32 cols (n) x 32 rows (m); 16 waves k-split (512 k each).
// All 8 B uint4 prefetched up front via NON-TEMPORAL loads (no L2/L3
// allocation -> no dirty-ws evictions on the critical read path).
// k-scramble: slot (c,t,quad,j) takes k = (w*64+c*16+quad*4+t)*8 + kp[j]
// from BOTH operands — same bijection, exact dot product.
__global__ __launch_bounds__(1024, 4) void qgemm_xp(
    const uint32_t* __restrict__ bq,     // packed int4 [N, K/8]
    const uint4*    __restrict__ xp,     // f16 [1024][32][8] (perm'd)
    const float*    __restrict__ sc,     // f32 [8192]
    const float*    __restrict__ bi,     // f32 [8192]
    float*          __restrict__ out) {  // f32 [32, 8192]
  __shared__ float red[16][32][33];      // [wave][n][m], stride 33 (66 KB)

  const int tid  = threadIdx.x;
  const int w    = tid >> 6;             // wave 0..15 -> k0 = w*512
  const int lane = tid & 63;
  const int l16  = lane & 15;
  const int quad = lane >> 4;
  const int n0   = blockIdx.x << 5;      // 32 n per WG

  // B u32x4 index: row*256 + w*16 + c*4 + quad; rows n0+l16, n0+l16+16
  const u32x4* bq4 = (const u32x4*)bq;
  const u32x4* bp0 = bq4 + (size_t)(n0 + l16) * 256 + (w << 4) + quad;
  const u32x4* bp1 = bp0 + (size_t)16 * 256;
  // A uint4 index: g*32 + m; g = w*64 + quad*4 + c*16 + t; m = l16 (+16)
  const uint4* ap  = xp + (size_t)(((w << 6) + (quad << 2)) * 32 + l16);

  // Prefetch ALL B: 4 chunks x 2 n-tiles = 8 outstanding HBM loads, nt.
  u32x4 b0[4], b1[4];
#pragma unroll
  for (int c = 0; c < 4; ++c) {
    b0[c] = __builtin_nontemporal_load(bp0 + c * 4);
    b1[c] = __builtin_nontemporal_load(bp1 + c * 4);
  }

  f32x4 acc00 = {0.f, 0.f, 0.f, 0.f};
  f32x4 acc01 = {0.f, 0.f, 0.f, 0.f};
  f32x4 acc10 = {0.f, 0.f, 0.f, 0.f};
  f32x4 acc11 = {0.f, 0.f, 0.f, 0.f};

  // A ping-pong over 16 t-groups; group g' -> uint4 offset ((g'>>2)*16+(g'&3))*32.
  uint4 a0c = ap[0], a1c = ap[16];       // group 0, both m-tiles
#pragma unroll
  for (int g = 0; g < 16; ++g) {
    const int gn  = (g + 1) & 15;        // last iter refetches group 0 (harmless)
    const int off = (((gn >> 2) * 16) + (gn & 3)) * 32;
    uint4 a0n = ap[off];
    uint4 a1n = ap[off + 16];

    const int c = g >> 2, t = g & 3;
    f16x8 fb0 = dq8(b0[c][t]);
    f16x8 fb1 = dq8(b1[c][t]);
    f16x8 fa0 = __builtin_bit_cast(f16x8, a0c);
    f16x8 fa1 = __builtin_bit_cast(f16x8, a1c);
    acc00 = __builtin_amdgcn_mfma_f32_16x16x32_f16(fa0, fb0, acc00, 0, 0, 0);
    acc01 = __builtin_amdgcn_mfma_f32_16x16x32_f16(fa1, fb0, acc01, 0, 0, 0);
    acc10 = __builtin_amdgcn_mfma_f32_16x16x32_f16(fa0, fb1, acc10, 0, 0, 0);
    acc11 = __builtin_amdgcn_mfma_f32_16x16x32_f16(fa1, fb1, acc11, 0, 0, 0);

    a0c = a0n; a1c = a1n;                // renamed away by full unroll
  }

  // C/D layout (verified round 4): n = lane&15, m = quad*4 + r.
#pragma unroll
  for (int r = 0; r < 4; ++r) {
    const int mr = (quad << 2) + r;
    red[w][l16][mr]           = acc00[r];
    red[w][l16][mr + 16]      = acc01[r];
    red[w][l16 + 16][mr]      = acc10[r];
    red[w][l16 + 16][mr + 16] = acc11[r];
  }

  __syncthreads();

  // 1024 threads = one output each: n = tid&31, m = tid>>5; stride-33 rows
  // make the 16-way read conflict-free across lanes.
  const int n = tid & 31;
  const int m = tid >> 5;
  float s = 0.f;
#pragma unroll
  for (int ww = 0; ww < 16; ++ww) s += red[ww][n][m];
  const int gn = n0 + n;
  __builtin_nontemporal_store(fmaf(s, sc[gn], bi[gn]),
                              &out[(size_t)m * N_DIM + gn]);
}

// -------- fallback (tiny ws): round-4 known-good direct kernel -------------
__global__ __launch_bounds__(512) void qgemm_direct(
    const uint32_t* __restrict__ bq, const float* __restrict__ x,
    const float* __restrict__ sc, const float* __restrict__ bi,
    float* __restrict__ out) {
  __shared__ float red[8][32][40];
  const int tid  = threadIdx.x;
  const int w    = tid >> 6;
  const int lane = tid & 63;
  const int l16  = lane & 15;
  const int quad = lane >> 4;
  const int n0   = blockIdx.x << 5;

  const uint4* bq4 = (const uint4*)bq;
  const uint4* bp0 = bq4 + (size_t)(n0 + l16) * 256 + (w << 5) + quad;
  const uint4* bp1 = bp0 + (size_t)16 * 256;
  const float* ap0 = x + (size_t)l16 * K_DIM + (w << 10) + (quad << 5);
  const float* ap1 = ap0 + (size_t)16 * K_DIM;

  f32x4 acc00 = {0.f,0.f,0.f,0.f}, acc01 = {0.f,0.f,0.f,0.f};
  f32x4 acc10 = {0.f,0.f,0.f,0.f}, acc11 = {0.f,0.f,0.f,0.f};
#pragma unroll
  for (int c = 0; c < 8; ++c) {
    const uint4 wb0 = bp0[c * 4];
    const uint4 wb1 = bp1[c * 4];
#pragma unroll
    for (int t = 0; t < 4; ++t) {
      const float* a0 = ap0 + c * 128 + t * 8;
      const float* a1 = ap1 + c * 128 + t * 8;
      f32x4 l0 = *(const f32x4*)a0, h0 = *(const f32x4*)(a0 + 4);
      f32x4 l1 = *(const f32x4*)a1, h1 = *(const f32x4*)(a1 + 4);
      f16x8 fa0, fa1;
#pragma unroll
      for (int s = 0; s < 4; ++s) {
        fa0[2*s] = (_Float16)l0[s]; fa0[2*s+1] = (_Float16)h0[s];
        fa1[2*s] = (_Float16)l1[s]; fa1[2*s+1] = (_Float16)h1[s];
      }
      const uint32_t e0 = (t==0)?wb0.x:(t==1)?wb0.y:(t==2)?wb0.z:wb0.w;
      const uint32_t e1 = (t==0)?wb1.x:(t==1)?wb1.y:(t==2)?wb1.z:wb1.w;
      f16x8 fb0 = dq8(e0);
      f16x8 fb1 = dq8(e1);
      acc00 = __builtin_amdgcn_mfma_f32_16x16x32_f16(fa0, fb0, acc00, 0, 0, 0);
      acc01 = __builtin_amdgcn_mfma_f32_16x16x32_f16(fa1, fb0, acc01, 0, 0, 0);
      acc10 = __builtin_amdgcn_mfma_f32_16x16x32_f16(fa0, fb1, acc10, 0, 0, 0);
      acc11 = __builtin_amdgcn_mfma_f32_16x16x32_f16(fa1, fb1, acc11, 0, 0, 0);
    }
  }
#pragma unroll
  for (int r = 0; r < 4; ++r) {
    const int mr = (quad << 2) + r;
    red[w][l16][mr]           = acc00[r];
    red[w][l16][mr + 16]      = acc01[r];
    red[w][l16 + 16][mr]      = acc10[r];
    red[w][l16 + 16][mr + 16] = acc11[r];
  }
  __syncthreads();
  const int n  = tid & 31;
  const int mh = tid >> 5;
  float s0 = 0.f, s1 = 0.f;
#pragma unroll
  for (int ww = 0; ww < 8; ++ww) { s0 += red[ww][n][mh]; s1 += red[ww][n][mh+16]; }
  const int gn = n0 + n;
  out[(size_t)mh * N_DIM + gn]        = fmaf(s0, sc[gn], bi[gn]);
  out[(size_t)(mh + 16) * N_DIM + gn] = fmaf(s1, sc[gn], bi[gn]);
}

extern "C" void kernel_launch(void* const* d_in, const int* in_sizes, int n_in,
                              void* d_out, int out_size, void* d_ws, size_t ws_size,
                              hipStream_t stream) {
  const float*    x  = (const float*)d_in[0];     // f32 [32,8192]
  const uint32_t* bq = (const uint32_t*)d_in[1];  // int32 [8192,1024]
  const float*    sc = (const float*)d_in[2];     // f32 [8192]
  const float*    bi = (const float*)d_in[3];     // f32 [8192]
  float*          y  = (float*)d_out;             // f32 [32,8192]

  const size_t XP_BYTES = (size_t)M_DIM * K_DIM * 2;  // 512 KB f16
  if (ws_size >= XP_BYTES) {                          // constant -> graph-safe
    uint4* xp = (uint4*)d_ws;
    xprep_kernel<<<128, 256, 0, stream>>>(x, xp);
    qgemm_xp<<<N_DIM / 32, 1024, 0, stream>>>(bq, xp, sc, bi, y);
  } else {
    qgemm_direct<<<N_DIM / 32, 512, 0, stream>>>(bq, x, sc, bi, y);
  }
}

// Round 4
// 91.694 us; speedup vs baseline: 1.0489x; 1.0489x over previous
//
#include <hip/hip_runtime.h>
#include <cstdint>

// y[m][n] = sum_k x[m][k] * (q[n][k] * scale[n]) + bias[n]
// M=32, K=8192, N=8192; q = signed int4 nibbles packed 8 per int32.
// Harness dtype reality (verified round 4): fp16 tensors are FLOAT32 on
// device (inputs and output); b_packed is int32.
//
// Round 8: FUSED single dispatch, LDS-staged A (no xprep, no workspace, no
// R1 gather). Rationale: (1) kernel-boundary L2 invalidation means xprep's
// output is always L3-resident-only at gemm start — R2 showed doubling that
// A-path cost ~4 us; staging from x (1 MB, per-XCD L2) removes it. (2) One
// dispatch removes a graph node + the ws round-trip. (3) The gemm becomes
// the only non-fill dispatch -> finally directly measurable in top-5.
// B path identical to harness-verified R0 (all-8 uint4 prefetch up front).
#define M_DIM 32
#define K_DIM 8192
#define N_DIM 8192

typedef _Float16 f16x8 __attribute__((ext_vector_type(8)));
typedef _Float16 f16x2 __attribute__((ext_vector_type(2)));
typedef float    f32x4 __attribute__((ext_vector_type(4)));
typedef uint32_t u32x4 __attribute__((ext_vector_type(4)));

// Magic-bias dequant: dword (8 nibbles) -> 8 exact f16 in [-8,7].
// t_s = ((w>>4s) & 0x000F000F) ^ 0x64086408 = f16x2 {1024+(n_s^8), 1024+(n_{s+4}^8)}
// minus 1032.0 -> {val(n_s), val(n_{s+4})} exactly (integers < 2048, exact f16).
// Fragment element j holds nibble kp[j] = (j>>1) + (j&1)*4; the A staging
// below bakes the SAME permutation into LDS, so the MFMA dot is exact.
__device__ __forceinline__ f16x8 dq8(uint32_t w) {
  union { uint32_t u[4]; f16x8 v; } r;
  const uint32_t MASK  = 0x000F000Fu;
  const uint32_t MAGIC = 0x64086408u;                 // f16x2 {1032, 1032}
  const f16x2 magic = __builtin_bit_cast(f16x2, MAGIC);
#pragma unroll
  for (int s = 0; s < 4; ++s) {
    uint32_t t = ((w >> (4 * s)) & MASK) ^ MAGIC;
    f16x2 h = __builtin_bit_cast(f16x2, t) - magic;   // v_pk_add_f16 (neg)
    r.u[s] = __builtin_bit_cast(uint32_t, h);
  }
  return r.v;
}

// -------- fused GEMM: 256 WGs x 1024 thr (16 waves), 32 n per WG ----------
// Wave w owns k in [w*512, w*512+512), processed as 4 c-stages of 128 k.
// Per c-stage the wave stages its A block x[0..31][kb..kb+128) into a
// wave-private 8 KB LDS buffer as perm'd f16 groups, then runs 4 MFMA iters.
// LDS group (r, p) at byte r*256 + ((p ^ (r&15))<<4) holds f16x8 with
// element j = x[r][kb + 8p + (j>>1) + (j&1)*4]  (nibble-pair perm).
// k identity: A group (c,t,quad): kb + 8*(quad*4+t) = w*512+c*128+quad*32+t*8
//           = B dword k-base for (c,t,quad)  -> exact dot product.
__global__ __launch_bounds__(1024, 4) void qgemm_fused2(
    const uint32_t* __restrict__ bq,     // packed int4 [N, K/8]
    const float*    __restrict__ x,      // f32 [32, 8192]
    const float*    __restrict__ sc,     // f32 [8192]
    const float*    __restrict__ bi,     // f32 [8192]
    float*          __restrict__ out) {  // f32 [32, 8192]
  // 128 KB: [0, 8K*w) wave staging buffers; reused as red[16][32][33] f32
  // (67.6 KB) behind a barrier after all MFMAs complete.
  __shared__ __align__(16) unsigned char lds[131072];

  const int tid  = threadIdx.x;
  const int w    = tid >> 6;             // wave 0..15 -> k0 = w*512
  const int lane = tid & 63;
  const int l16  = lane & 15;
  const int quad = lane >> 4;
  const int n0   = blockIdx.x << 5;      // 32 n per WG

  // ---- B prefetch first: whole wave HBM demand in flight at t=0 ----------
  // uint4 index: row*256 + w*16 + c*4 + quad; rows n0+l16, n0+l16+16.
  const u32x4* bq4 = (const u32x4*)bq;
  const u32x4* bp0 = bq4 + (size_t)(n0 + l16) * 256 + (w << 4) + quad;
  const u32x4* bp1 = bp0 + (size_t)16 * 256;
  u32x4 b0[4], b1[4];
#pragma unroll
  for (int c = 0; c < 4; ++c) { b0[c] = bp0[c * 4]; b1[c] = bp1[c * 4]; }

  char* stg = (char*)lds + (w << 13);    // wave-private 8 KB staging

  f32x4 acc00 = {0.f, 0.f, 0.f, 0.f};
  f32x4 acc01 = {0.f, 0.f, 0.f, 0.f};
  f32x4 acc10 = {0.f, 0.f, 0.f, 0.f};
  f32x4 acc11 = {0.f, 0.f, 0.f, 0.f};

#pragma unroll
  for (int c = 0; c < 4; ++c) {
    const int kb = (w << 9) + (c << 7);  // k float base of this stage

    // ---- stage: 8 rounds; lane (quad,l16) -> row r=j*4+quad, group p=l16.
    // Loads are x-row-local (L2 hits after first touch; x = 1 MB/XCD).
#pragma unroll
    for (int j = 0; j < 8; ++j) {
      const int r = (j << 2) + quad;
      const float* px = x + (size_t)r * K_DIM + kb + (l16 << 3);
      f32x4 lo = *(const f32x4*)px;        // k 8p..8p+3
      f32x4 hi = *(const f32x4*)(px + 4);  // k 8p+4..8p+7
      union { f16x8 v; u32x4 q; } h;
#pragma unroll
      for (int s = 0; s < 4; ++s) {
        h.v[2 * s]     = (_Float16)lo[s];  // nibble-pair perm {lo_s, hi_s}
        h.v[2 * s + 1] = (_Float16)hi[s];
      }
      const int slot = l16 ^ (r & 15);     // XOR swizzle (write side)
      *reinterpret_cast<u32x4*>(stg + (r << 8) + (slot << 4)) = h.q;
    }
    // compiler inserts lgkmcnt before the dependent ds_reads (wave-private
    // buffer -> no barrier needed).

    // ---- consume: 4 MFMA iters over this stage ----------------------------
#pragma unroll
    for (int t = 0; t < 4; ++t) {
      const int pA = (quad << 2) + t;
      const int s0 = (pA ^ l16) << 4;      // XOR swizzle (read side, m&15=l16)
      const u32x4 a0 = *reinterpret_cast<const u32x4*>(stg + (l16 << 8) + s0);
      const u32x4 a1 = *reinterpret_cast<const u32x4*>(stg + ((l16 + 16) << 8) + s0);
      f16x8 fa0 = __builtin_bit_cast(f16x8, a0);
      f16x8 fa1 = __builtin_bit_cast(f16x8, a1);
      f16x8 fb0 = dq8(b0[c][t]);
      f16x8 fb1 = dq8(b1[c][t]);
      acc00 = __builtin_amdgcn_mfma_f32_16x16x32_f16(fa0, fb0, acc00, 0, 0, 0);
      acc01 = __builtin_amdgcn_mfma_f32_16x16x32_f16(fa1, fb0, acc01, 0, 0, 0);
      acc10 = __builtin_amdgcn_mfma_f32_16x16x32_f16(fa0, fb1, acc10, 0, 0, 0);
      acc11 = __builtin_amdgcn_mfma_f32_16x16x32_f16(fa1, fb1, acc11, 0, 0, 0);
    }
  }

  // ---- cross-wave k-reduction (staging region reused as red) -------------
  __syncthreads();                       // all waves done reading staging
  float (*red)[32][33] = reinterpret_cast<float (*)[32][33]>(lds);

  // C/D layout (verified round 4): n = lane&15, m = quad*4 + r.
#pragma unroll
  for (int r = 0; r < 4; ++r) {
    const int mr = (quad << 2) + r;
    red[w][l16][mr]           = acc00[r];
    red[w][l16][mr + 16]      = acc01[r];
    red[w][l16 + 16][mr]      = acc10[r];
    red[w][l16 + 16][mr + 16] = acc11[r];
  }

  __syncthreads();

  // 1024 threads = one output each: n = tid&31, m = tid>>5; stride-33 rows
  // make the 16-way read conflict-free across lanes.
  const int n = tid & 31;
  const int m = tid >> 5;
  float s = 0.f;
#pragma unroll
  for (int ww = 0; ww < 16; ++ww) s += red[ww][n][m];
  const int gn = n0 + n;
  out[(size_t)m * N_DIM + gn] = fmaf(s, sc[gn], bi[gn]);
}

extern "C" void kernel_launch(void* const* d_in, const int* in_sizes, int n_in,
                              void* d_out, int out_size, void* d_ws, size_t ws_size,
                              hipStream_t stream) {
  const float*    x  = (const float*)d_in[0];     // f32 [32,8192]
  const uint32_t* bq = (const uint32_t*)d_in[1];  // int32 [8192,1024]
  const float*    sc = (const float*)d_in[2];     // f32 [8192]
  const float*    bi = (const float*)d_in[3];     // f32 [8192]
  float*          y  = (float*)d_out;             // f32 [32,8192]
  (void)d_ws; (void)ws_size;                      // workspace deliberately unused

  qgemm_fused2<<<N_DIM / 32, 1024, 0, stream>>>(bq, x, sc, bi, y);
}